// Round 13
// baseline (118.840 us; speedup 1.0000x reference)
//
#include <hip/hip_runtime.h>
#include <cstdint>
#include <cstddef>

// SoftTree: out[b,o] = sum_l ((x@pw[o])[b,l] + pb[o,l]) * p[b,l]
// B=4096, I=512, O=64, L=256, GATES=255, depth 8.
// p is stored PERMUTED: p2[b*256 + j] = prob(leaf perm(j)), perm(j) =
// ((j&15)<<4)|(j>>4) (involution) -> epilogue reads 8 consecutive floats.
#define GATES 255

typedef __attribute__((ext_vector_type(8))) short bf16x8;   // 8 bf16 = 4 VGPR
typedef __attribute__((ext_vector_type(4))) float f32x4;

__device__ __forceinline__ short f2bf(float f) {
  union { float f; uint32_t u; } c; c.f = f;
  uint32_t r = c.u + 0x7FFFu + ((c.u >> 16) & 1u);   // RNE
  return (short)(r >> 16);
}

#define GLOAD16(gp, lp) __builtin_amdgcn_global_load_lds( \
    (const __attribute__((address_space(1))) uint32_t*)(gp), \
    (__attribute__((address_space(3))) uint32_t*)(lp), 16, 0, 0)

// ---------------- gw[i][255] fp32 -> gwt[g][i] bf16 (g=255 padded w/ zeros) --
// Tiny (32 blocks, ~1.5us); must precede the fused kernel's gating blocks.
__global__ __launch_bounds__(256) void k_prepgw(const float* __restrict__ gw,
                                                short* __restrict__ gwt) {
  __shared__ short t[64][65];
  const int bx = blockIdx.x;            // 8 iblk * 4 gblk
  const int tid = threadIdx.x;
  const int c = tid & 63, r0 = tid >> 6;
  const int ib = bx >> 2, gb = bx & 3;
  const int i0 = ib << 6, g0 = gb << 6;
#pragma unroll
  for (int rr = 0; rr < 16; ++rr) {
    const int i = rr * 4 + r0;
    const int g = g0 + c;
    t[i][c] = (g < GATES) ? f2bf(gw[(size_t)(i0 + i) * GATES + g]) : (short)0;
  }
  __syncthreads();
#pragma unroll
  for (int rr = 0; rr < 16; ++rr) {
    const int gg = rr * 4 + r0;
    gwt[(size_t)(g0 + gg) * 512 + i0 + c] = t[c][gg];
  }
}

// ---------------- fused prep: x-convert | pw-transpose | gating --------------
// All three are mutually independent (gating reads fp32 x directly with
// reg-staged conversion; only gwt is a cross-launch dep) -> one launch runs
// them CONCURRENTLY across CUs instead of 3 serial dispatches (R12: ~18us
// serial -> ~max(10,6,2) fused).
// blocks [0,2048): x fp32 -> bf16
// blocks [2048,4096): pw[o][i][l] -> pwt[o][l][i] bf16 (vectorized)
// blocks [4096,4224): gating GEMM + sigmoid + permuted leaf products
__global__ __launch_bounds__(256, 1) void k_fused(const float* __restrict__ x,
                                                  short* __restrict__ xb,
                                                  const float* __restrict__ pw,
                                                  short* __restrict__ pwt,
                                                  const short* __restrict__ gwt,
                                                  const float* __restrict__ gb,
                                                  float* __restrict__ p) {
  __shared__ __align__(16) char smem[70144];
  const int bx = blockIdx.x;
  const int tid = threadIdx.x;

  if (bx < 2048) {                      // ---- convert x ----
    const int i = bx * 256 + tid;       // 524288 float4s
    const float4 v = ((const float4*)x)[i];
    short4 s;
    s.x = f2bf(v.x); s.y = f2bf(v.y); s.z = f2bf(v.z); s.w = f2bf(v.w);
    ((short4*)xb)[i] = s;
    return;
  }

  if (bx < 4096) {                      // ---- pw transpose (vectorized) ----
    short* t = (short*)smem;            // [64][72] pitch 72
    const int b2 = bx - 2048;           // 64 o * 8 iblk * 4 lblk
    const int o = b2 >> 5;
    const int ib = (b2 >> 2) & 7;
    const int lb = b2 & 3;
    const int i0 = ib << 6, l0 = lb << 6;
    const int r = tid >> 4;             // 0..15
    const int cg = tid & 15;            // 0..15 (group of 4 cols)
    const float* src = pw + ((size_t)o * 512 + i0) * 256 + l0;
#pragma unroll
    for (int rr = 0; rr < 4; ++rr) {    // 4 rows/thread, float4 over l
      const int i = rr * 16 + r;
      const float4 v = *(const float4*)(src + (size_t)i * 256 + cg * 4);
      short4 s;
      s.x = f2bf(v.x); s.y = f2bf(v.y); s.z = f2bf(v.z); s.w = f2bf(v.w);
      *(short4*)(&t[i * 72 + cg * 4]) = s;
    }
    __syncthreads();
    short* dst = pwt + ((size_t)o * 256 + l0) * 512 + i0;
#pragma unroll
    for (int rr = 0; rr < 4; ++rr) {    // 4 l-rows/thread, short4 over i
      const int ll = rr * 16 + r;
      short4 s;
      s.x = t[(cg * 4 + 0) * 72 + ll];
      s.y = t[(cg * 4 + 1) * 72 + ll];
      s.z = t[(cg * 4 + 2) * 72 + ll];
      s.w = t[(cg * 4 + 3) * 72 + ll];
      *(short4*)(dst + (size_t)ll * 512 + cg * 4) = s;
    }
    return;
  }

  // ---- gating: BM=32 rows, BN=256 gates, K=512; 4 waves 2x2 ----
  short* a_lds = (short*)smem;                    // [32][64]   4KB
  short* b_lds = (short*)(smem + 4096);           // [256][64] 32KB
  float* gs    = (float*)(smem + 36864);          // [32][260] 33.25KB

  const int b0 = (bx - 4096) << 5;      // 128 gating blocks
  const int lane = tid & 63;
  const int w = tid >> 6;
  const int wr = w >> 1, wc = w & 1;    // wave tile 16x128

  f32x4 acc[8];
#pragma unroll
  for (int nf = 0; nf < 8; ++nf) {
    acc[nf][0] = 0.f; acc[nf][1] = 0.f; acc[nf][2] = 0.f; acc[nf][3] = 0.f;
  }

  const int ar = tid >> 3, ac = (tid & 7) << 3;   // A reg-stage coords
  for (int s = 0; s < 8; ++s) {
    const int i0 = s << 6;
    __syncthreads();
    {                                   // A: reg-staged fp32 -> bf16, 8/thread
      const float* xr = x + (size_t)(b0 + ar) * 512 + i0 + ac;
      const float4 v0 = *(const float4*)(xr);
      const float4 v1 = *(const float4*)(xr + 4);
      bf16x8 a8;
      a8[0] = f2bf(v0.x); a8[1] = f2bf(v0.y);
      a8[2] = f2bf(v0.z); a8[3] = f2bf(v0.w);
      a8[4] = f2bf(v1.x); a8[5] = f2bf(v1.y);
      a8[6] = f2bf(v1.z); a8[7] = f2bf(v1.w);
      *(bf16x8*)(a_lds + ar * 64 + ac) = a8;
    }
#pragma unroll
    for (int sw = 0; sw < 8; ++sw) {    // B: 2048 x 16B chunks via gload_lds
      const int chunk = sw * 256 + tid;
      const int r = chunk >> 3, cc = (chunk & 7) << 3;
      GLOAD16(gwt + (size_t)r * 512 + i0 + cc, b_lds + chunk * 8);
    }
    __syncthreads();
#pragma unroll
    for (int kk = 0; kk < 2; ++kk) {
      const int kb = (kk << 5) + ((lane >> 4) << 3);
      bf16x8 af, bfr[8];
      {
        const int row = (wr << 4) + (lane & 15);
        af = *(const bf16x8*)(a_lds + row * 64 + kb);
      }
#pragma unroll
      for (int nf = 0; nf < 8; ++nf) {
        const int row = (wc << 7) + (nf << 4) + (lane & 15);
        bfr[nf] = *(const bf16x8*)(b_lds + row * 64 + kb);
      }
#pragma unroll
      for (int nf = 0; nf < 8; ++nf)
        acc[nf] = __builtin_amdgcn_mfma_f32_16x16x32_bf16(
            af, bfr[nf], acc[nf], 0, 0, 0);
    }
  }

  // sigmoid(logit + gb) -> gs[b_local][g]
  const int grp = lane >> 4, lcol = lane & 15;
#pragma unroll
  for (int nf = 0; nf < 8; ++nf) {
    const int g = (wc << 7) + (nf << 4) + lcol;
    const float bias = (g < GATES) ? gb[g] : 0.f;
#pragma unroll
    for (int rg = 0; rg < 4; ++rg) {
      const int bl = (wr << 4) + (grp << 2) + rg;
      const float z = acc[nf][rg] + bias;
      gs[bl * 260 + g] = 1.f / (1.f + __expf(-z));
    }
  }
  __syncthreads();

  // leaf probs, permuted: thread tid handles leaf l=perm(tid) for all 32 rows
  const int l = ((tid & 15) << 4) | (tid >> 4);
  for (int r = 0; r < 32; ++r) {
    float prob = 1.f;
    int index = 1;
#pragma unroll
    for (int j = 0; j < 8; ++j) {
      const int bit = (l >> (7 - j)) & 1;
      const float gg = gs[r * 260 + index - 1];
      prob *= bit ? (1.f - gg) : gg;
      index = 2 * index + bit;
    }
    p[(size_t)(b0 + r) * 256 + tid] = prob;
  }
}

// ---------------- main fused GEMM (champion, frozen since R8/R11) -----------
// BM=128, BN=256(=L), BK=64; 4 waves 2x2; wave tile 64x128; serial 2-barrier
// loop; 0-conflict both-sides swizzle (blk ^= row&7); 48KB LDS -> 2 blocks/CU.
// Pinned ~90us across 7 structural variants (R3-R12).
__global__ __launch_bounds__(256, 2) void k_main(const short* __restrict__ xb,
                                                 const short* __restrict__ pwt,
                                                 const float* __restrict__ p,
                                                 const float* __restrict__ pb,
                                                 float* __restrict__ out) {
  __shared__ short a_lds[128 * 64];   // 16KB
  __shared__ short b_lds[256 * 64];   // 32KB; total 48KB exactly

  const int bx = blockIdx.x;          // 64 o * 32 bm = 2048; o-major
  const int o = bx >> 5;
  const int bm0 = (bx & 31) << 7;
  const int tid = threadIdx.x;
  const int lane = tid & 63;
  const int w = tid >> 6;
  const int wr = w >> 1;              // wave row (m): 0..1
  const int wc = w & 1;               // wave col (n): 0..1

  const short* Ab = xb + (size_t)bm0 * 512;
  const short* Bb = pwt + (size_t)o * (256 * 512);

  f32x4 acc[4][8];
#pragma unroll
  for (int mf = 0; mf < 4; ++mf)
#pragma unroll
    for (int nf = 0; nf < 8; ++nf) {
      acc[mf][nf][0] = 0.f; acc[mf][nf][1] = 0.f;
      acc[mf][nf][2] = 0.f; acc[mf][nf][3] = 0.f;
    }

  for (int s = 0; s < 8; ++s) {       // K = 8 stages of 64
    const int i0 = s << 6;
    __syncthreads();                  // previous compute done before overwrite
#pragma unroll
    for (int sw = 0; sw < 4; ++sw) {  // A: 1024 x 16B chunks
      const int c = sw * 256 + tid;
      const int r = c >> 3;
      const int gblk = (c & 7) ^ (r & 7);          // inverse-swizzled source
      GLOAD16(Ab + (size_t)r * 512 + i0 + (gblk << 3), a_lds + c * 8);
    }
#pragma unroll
    for (int sw = 0; sw < 8; ++sw) {  // B: 2048 x 16B chunks
      const int c = sw * 256 + tid;
      const int r = c >> 3;
      const int gblk = (c & 7) ^ (r & 7);
      GLOAD16(Bb + (size_t)r * 512 + i0 + (gblk << 3), b_lds + c * 8);
    }
    __syncthreads();                  // vmcnt(0) drained by compiler
#pragma unroll
    for (int kk = 0; kk < 2; ++kk) {
      const int kblk = (kk << 2) + (lane >> 4);    // 16B block 0..7
      bf16x8 af[4], bfr[8];
#pragma unroll
      for (int mf = 0; mf < 4; ++mf) {
        const int row = (wr << 6) + (mf << 4) + (lane & 15);
        af[mf] = *(const bf16x8*)(a_lds + row * 64 + ((kblk ^ (row & 7)) << 3));
      }
#pragma unroll
      for (int nf = 0; nf < 8; ++nf) {
        const int row = (wc << 7) + (nf << 4) + (lane & 15);
        bfr[nf] = *(const bf16x8*)(b_lds + row * 64 + ((kblk ^ (row & 7)) << 3));
      }
#pragma unroll
      for (int mf = 0; mf < 4; ++mf)
#pragma unroll
        for (int nf = 0; nf < 8; ++nf)
          acc[mf][nf] = __builtin_amdgcn_mfma_f32_16x16x32_bf16(
              af[mf], bfr[nf], acc[mf][nf], 0, 0, 0);
    }
  }

  // epilogue: D lane map (m89): col(l)=lane&15, row(b)=(lane>>4)*4+reg.
  // l = wc*128 + nf*16 + lcol; perm(l) = lcol*16 + wc*8 + nf -> p2 rows give
  // nf=0..7 contiguously at p[b*256 + lcol*16 + wc*8].
  __syncthreads();                    // K-loop reads done; reuse a_lds as red[]
  float* red = (float*)a_lds;         // red[2][128] overlay, 1KB
  const int lcol = lane & 15;
  const int grp = lane >> 4;
  float pbv[8];
#pragma unroll
  for (int nf = 0; nf < 8; ++nf)
    pbv[nf] = pb[(size_t)o * 256 + (wc << 7) + (nf << 4) + lcol];
#pragma unroll
  for (int mf = 0; mf < 4; ++mf) {
#pragma unroll
    for (int rg = 0; rg < 4; ++rg) {
      const int bl = (wr << 6) + (mf << 4) + (grp << 2) + rg;  // b within tile
      const int b = bm0 + bl;
      const float4* pp =
          (const float4*)(p + (size_t)b * 256 + lcol * 16 + (wc << 3));
      const float4 p0 = pp[0], p1 = pp[1];     // nf=0..3, nf=4..7
      float v = (acc[mf][0][rg] + pbv[0]) * p0.x
              + (acc[mf][1][rg] + pbv[1]) * p0.y
              + (acc[mf][2][rg] + pbv[2]) * p0.z
              + (acc[mf][3][rg] + pbv[3]) * p0.w
              + (acc[mf][4][rg] + pbv[4]) * p1.x
              + (acc[mf][5][rg] + pbv[5]) * p1.y
              + (acc[mf][6][rg] + pbv[6]) * p1.z
              + (acc[mf][7][rg] + pbv[7]) * p1.w;
      // reduce over the 16 lanes (same b, different l residues)
      v += __shfl_xor(v, 1);
      v += __shfl_xor(v, 2);
      v += __shfl_xor(v, 4);
      v += __shfl_xor(v, 8);
      if (lcol == 0) red[wc * 128 + bl] = v;
    }
  }
  __syncthreads();
  if (tid < 128) {
    out[(size_t)(bm0 + tid) * 64 + o] = red[tid] + red[128 + tid];
  }
}

extern "C" void kernel_launch(void* const* d_in, const int* in_sizes, int n_in,
                              void* d_out, int out_size, void* d_ws, size_t ws_size,
                              hipStream_t stream) {
  (void)in_sizes; (void)n_in; (void)out_size; (void)ws_size;
  const float* x  = (const float*)d_in[0];
  const float* gw = (const float*)d_in[1];
  const float* gb = (const float*)d_in[2];
  const float* pw = (const float*)d_in[3];
  const float* pb = (const float*)d_in[4];
  // d_in[5] leaf_idx / d_in[6] leaf_bit: tree is deterministic, recomputed in-kernel.
  float* out = (float*)d_out;

  char* ws = (char*)d_ws;
  short* xbuf = (short*)(ws);                              // 4 MB bf16 x
  short* gwt  = (short*)(ws + ((size_t)4 << 20));          // 256 KB bf16 gw_t
  short* pwt  = (short*)(ws + ((size_t)4 << 20) + (256 << 10));  // 16 MB bf16 pw_t
  float* p    = (float*)(ws + ((size_t)20 << 20) + (256 << 10)); // 4 MB leaf probs (permuted)

  k_prepgw<<<32, 256, 0, stream>>>(gw, gwt);
  k_fused<<<4224, 256, 0, stream>>>(x, xbuf, pw, pwt, gwt, gb, p);
  k_main<<<2048, 256, 0, stream>>>(xbuf, pwt, p, pb, out);
}

// Round 14
// 111.314 us; speedup vs baseline: 1.0676x; 1.0676x over previous
//
#include <hip/hip_runtime.h>
#include <cstdint>
#include <cstddef>

// SoftTree: out[b,o] = sum_l ((x@pw[o])[b,l] + pb[o,l]) * p[b,l]
// B=4096, I=512, O=64, L=256, GATES=255, depth 8.
// Configuration: R10 champion (best measured total, 111.7us).
#define GATES 255

typedef __attribute__((ext_vector_type(8))) short bf16x8;   // 8 bf16 = 4 VGPR
typedef __attribute__((ext_vector_type(4))) float f32x4;

__device__ __forceinline__ short f2bf(float f) {
  union { float f; uint32_t u; } c; c.f = f;
  uint32_t r = c.u + 0x7FFFu + ((c.u >> 16) & 1u);   // RNE
  return (short)(r >> 16);
}

#define GLOAD16(gp, lp) __builtin_amdgcn_global_load_lds( \
    (const __attribute__((address_space(1))) uint32_t*)(gp), \
    (__attribute__((address_space(3))) uint32_t*)(lp), 16, 0, 0)

// ---------------- merged prep: x->bf16 | gw transpose | pw transpose ---------
__global__ __launch_bounds__(256) void k_prep(const float* __restrict__ x,
                                              short* __restrict__ xb,
                                              const float* __restrict__ gw,
                                              short* __restrict__ gwt,
                                              const float* __restrict__ pw,
                                              short* __restrict__ pwt) {
  __shared__ short t[64][65];
  const int bx = blockIdx.x;
  const int tid = threadIdx.x;

  if (bx < 2048) {                      // ---- convert x ----
    const int i = bx * 256 + tid;       // 524288 float4s
    const float4 v = ((const float4*)x)[i];
    short4 s;
    s.x = f2bf(v.x); s.y = f2bf(v.y); s.z = f2bf(v.z); s.w = f2bf(v.w);
    ((short4*)xb)[i] = s;
    return;
  }

  const int c = tid & 63, r0 = tid >> 6;

  if (bx < 2080) {                      // ---- gw transpose ----
    const int b2 = bx - 2048;           // 8 iblk * 4 gblk
    const int ib = b2 >> 2, gb = b2 & 3;
    const int i0 = ib << 6, g0 = gb << 6;
#pragma unroll
    for (int rr = 0; rr < 16; ++rr) {
      const int i = rr * 4 + r0;
      const int g = g0 + c;
      t[i][c] = (g < GATES) ? f2bf(gw[(size_t)(i0 + i) * GATES + g]) : (short)0;
    }
    __syncthreads();
#pragma unroll
    for (int rr = 0; rr < 16; ++rr) {
      const int gg = rr * 4 + r0;
      gwt[(size_t)(g0 + gg) * 512 + i0 + c] = t[c][gg];
    }
    return;
  }

  // ---- pw transpose ----
  const int b2 = bx - 2080;             // 64 o * 8 iblk * 4 lblk
  const int o = b2 >> 5;
  const int ib = (b2 >> 2) & 7;
  const int lb = b2 & 3;
  const int i0 = ib << 6, l0 = lb << 6;
  const float* src = pw + ((size_t)o * 512 + i0) * 256 + l0;
#pragma unroll
  for (int rr = 0; rr < 16; ++rr) {
    const int i = rr * 4 + r0;
    t[i][c] = f2bf(src[(size_t)i * 256 + c]);            // coalesced over l
  }
  __syncthreads();
  short* dst = pwt + ((size_t)o * 256 + l0) * 512 + i0;
#pragma unroll
  for (int rr = 0; rr < 16; ++rr) {
    const int ll = rr * 4 + r0;
    dst[(size_t)ll * 512 + c] = t[c][ll];                // coalesced over i
  }
}

// ---------------- gating via MFMA + fused sigmoid + leaf products ------------
// BM=32 rows x 128 blocks; 4 waves 2x2; wave tile 16x128.
__global__ __launch_bounds__(256, 1) void k_gate(const short* __restrict__ xb,
                                                 const short* __restrict__ gwt,
                                                 const float* __restrict__ gb,
                                                 float* __restrict__ p) {
  __shared__ short a_lds[32 * 64];     // 4KB
  __shared__ short b_lds[256 * 64];    // 32KB
  __shared__ float gs[32][260];        // sigmoid gates, 33KB

  const int b0 = blockIdx.x << 5;      // 128 blocks
  const int tid = threadIdx.x;
  const int lane = tid & 63;
  const int w = tid >> 6;
  const int wr = w >> 1, wc = w & 1;   // wave tile 16x128

  const short* Ab = xb + (size_t)b0 * 512;

  f32x4 acc[8];
#pragma unroll
  for (int nf = 0; nf < 8; ++nf) {
    acc[nf][0] = 0.f; acc[nf][1] = 0.f; acc[nf][2] = 0.f; acc[nf][3] = 0.f;
  }

  for (int s = 0; s < 8; ++s) {
    const int i0 = s << 6;
    __syncthreads();
    {                                  // A: 256 x 16B chunks, 1/thread
      const int c = tid;
      const int r = c >> 3, cc = (c & 7) << 3;
      GLOAD16(Ab + (size_t)r * 512 + i0 + cc, a_lds + c * 8);
    }
#pragma unroll
    for (int sw = 0; sw < 8; ++sw) {   // B: 2048 x 16B chunks
      const int chunk = sw * 256 + tid;
      const int r = chunk >> 3, cc = (chunk & 7) << 3;
      GLOAD16(gwt + (size_t)r * 512 + i0 + cc, b_lds + chunk * 8);
    }
    __syncthreads();
#pragma unroll
    for (int kk = 0; kk < 2; ++kk) {
      const int kb = (kk << 5) + ((lane >> 4) << 3);
      bf16x8 af, bfr[8];
      {
        const int row = (wr << 4) + (lane & 15);
        af = *(const bf16x8*)(a_lds + row * 64 + kb);
      }
#pragma unroll
      for (int nf = 0; nf < 8; ++nf) {
        const int row = (wc << 7) + (nf << 4) + (lane & 15);
        bfr[nf] = *(const bf16x8*)(b_lds + row * 64 + kb);
      }
#pragma unroll
      for (int nf = 0; nf < 8; ++nf)
        acc[nf] = __builtin_amdgcn_mfma_f32_16x16x32_bf16(
            af, bfr[nf], acc[nf], 0, 0, 0);
    }
  }

  // sigmoid(logit + gb) -> gs[b_local][g]
  const int grp = lane >> 4, lcol = lane & 15;
#pragma unroll
  for (int nf = 0; nf < 8; ++nf) {
    const int g = (wc << 7) + (nf << 4) + lcol;
    const float bias = (g < GATES) ? gb[g] : 0.f;
#pragma unroll
    for (int rg = 0; rg < 4; ++rg) {
      const int bl = (wr << 4) + (grp << 2) + rg;
      const float z = acc[nf][rg] + bias;
      gs[bl][g] = 1.f / (1.f + __expf(-z));
    }
  }
  __syncthreads();

  // leaf probs: thread handles leaf l=tid for all 32 rows
  const int l = tid;
  for (int r = 0; r < 32; ++r) {
    float prob = 1.f;
    int index = 1;
#pragma unroll
    for (int j = 0; j < 8; ++j) {
      const int bit = (l >> (7 - j)) & 1;
      const float gg = gs[r][index - 1];
      prob *= bit ? (1.f - gg) : gg;
      index = 2 * index + bit;
    }
    p[(size_t)(b0 + r) * 256 + l] = prob;
  }
}

// ---------------- main fused GEMM (R8 structure, 8 waves, 4 waves/SIMD) -----
// BM=128, BN=256(=L), BK=64; 8 waves 2Mx4N; wave tile 64x64; acc[4][4]=64 AGPR.
// Serial 2-barrier loop; 0-conflict both-sides swizzle (blk ^= row&7);
// 48KB LDS -> 2 blocks/CU. Pinned ~90us across 8 variants (R3-R13); only the
// bank-conflict fix ever moved it. Structure ceiling at K=512.
__global__ __launch_bounds__(512, 4) void k_main(const short* __restrict__ xb,
                                                 const short* __restrict__ pwt,
                                                 const float* __restrict__ p,
                                                 const float* __restrict__ pb,
                                                 float* __restrict__ out) {
  __shared__ short a_lds[128 * 64];   // 16KB
  __shared__ short b_lds[256 * 64];   // 32KB; total 48KB -> 2 blocks/CU

  const int bx = blockIdx.x;          // 64 o * 32 bm = 2048; o-major
  const int o = bx >> 5;
  const int bm0 = (bx & 31) << 7;
  const int tid = threadIdx.x;
  const int lane = tid & 63;
  const int w = tid >> 6;             // 0..7
  const int wr = w >> 2;              // 0..1  (m half: 64 rows)
  const int wc = w & 3;               // 0..3  (n quarter: 64 cols)

  const short* Ab = xb + (size_t)bm0 * 512;
  const short* Bb = pwt + (size_t)o * (256 * 512);

  f32x4 acc[4][4];
#pragma unroll
  for (int mf = 0; mf < 4; ++mf)
#pragma unroll
    for (int nf = 0; nf < 4; ++nf) {
      acc[mf][nf][0] = 0.f; acc[mf][nf][1] = 0.f;
      acc[mf][nf][2] = 0.f; acc[mf][nf][3] = 0.f;
    }

  for (int s = 0; s < 8; ++s) {       // K = 8 stages of 64
    const int i0 = s << 6;
    __syncthreads();                  // previous compute done before overwrite
#pragma unroll
    for (int j = 0; j < 2; ++j) {     // A: 1024 x 16B chunks, 2/thread
      const int c = j * 512 + tid;
      const int r = c >> 3;
      const int gblk = (c & 7) ^ (r & 7);          // inverse-swizzled source
      GLOAD16(Ab + (size_t)r * 512 + i0 + (gblk << 3), a_lds + c * 8);
    }
#pragma unroll
    for (int j = 0; j < 4; ++j) {     // B: 2048 x 16B chunks, 4/thread
      const int c = j * 512 + tid;
      const int r = c >> 3;
      const int gblk = (c & 7) ^ (r & 7);
      GLOAD16(Bb + (size_t)r * 512 + i0 + (gblk << 3), b_lds + c * 8);
    }
    __syncthreads();                  // vmcnt(0) drained by compiler
#pragma unroll
    for (int kk = 0; kk < 2; ++kk) {
      const int kblk = (kk << 2) + (lane >> 4);    // 16B block 0..7
      bf16x8 af[4], bfr[4];
#pragma unroll
      for (int mf = 0; mf < 4; ++mf) {
        const int row = (wr << 6) + (mf << 4) + (lane & 15);
        af[mf] = *(const bf16x8*)(a_lds + row * 64 + ((kblk ^ (row & 7)) << 3));
      }
#pragma unroll
      for (int nf = 0; nf < 4; ++nf) {
        const int row = (wc << 6) + (nf << 4) + (lane & 15);
        bfr[nf] = *(const bf16x8*)(b_lds + row * 64 + ((kblk ^ (row & 7)) << 3));
      }
#pragma unroll
      for (int mf = 0; mf < 4; ++mf)
#pragma unroll
        for (int nf = 0; nf < 4; ++nf)
          acc[mf][nf] = __builtin_amdgcn_mfma_f32_16x16x32_bf16(
              af[mf], bfr[nf], acc[mf][nf], 0, 0, 0);
    }
  }

  // epilogue: D lane map (m89): col(l)=lane&15, row(b)=(lane>>4)*4+reg
  __syncthreads();                    // K-loop reads done; reuse a_lds as red[]
  float* red = (float*)a_lds;         // red[4][128] overlay, 2KB
  const int grp = lane >> 4;
  const int lcol = lane & 15;
  float pbv[4];
#pragma unroll
  for (int nf = 0; nf < 4; ++nf)
    pbv[nf] = pb[(size_t)o * 256 + (wc << 6) + (nf << 4) + lcol];
#pragma unroll
  for (int mf = 0; mf < 4; ++mf) {
#pragma unroll
    for (int rg = 0; rg < 4; ++rg) {
      const int bl = (wr << 6) + (mf << 4) + (grp << 2) + rg;  // b within tile
      const int b = bm0 + bl;
      float v = 0.f;
#pragma unroll
      for (int nf = 0; nf < 4; ++nf) {
        const int l = (wc << 6) + (nf << 4) + lcol;
        v += (acc[mf][nf][rg] + pbv[nf]) * p[(size_t)b * 256 + l];
      }
      // reduce over the 16 lanes (same b, different l residues)
      v += __shfl_xor(v, 1);
      v += __shfl_xor(v, 2);
      v += __shfl_xor(v, 4);
      v += __shfl_xor(v, 8);
      if (lcol == 0) red[wc * 128 + bl] = v;
    }
  }
  __syncthreads();
  if (tid < 128) {
    out[(size_t)(bm0 + tid) * 64 + o] =
        red[tid] + red[128 + tid] + red[256 + tid] + red[384 + tid];
  }
}

extern "C" void kernel_launch(void* const* d_in, const int* in_sizes, int n_in,
                              void* d_out, int out_size, void* d_ws, size_t ws_size,
                              hipStream_t stream) {
  (void)in_sizes; (void)n_in; (void)out_size; (void)ws_size;
  const float* x  = (const float*)d_in[0];
  const float* gw = (const float*)d_in[1];
  const float* gb = (const float*)d_in[2];
  const float* pw = (const float*)d_in[3];
  const float* pb = (const float*)d_in[4];
  // d_in[5] leaf_idx / d_in[6] leaf_bit: tree is deterministic, recomputed in-kernel.
  float* out = (float*)d_out;

  char* ws = (char*)d_ws;
  short* xbuf = (short*)(ws);                              // 4 MB bf16 x
  short* gwt  = (short*)(ws + ((size_t)4 << 20));          // 256 KB bf16 gw_t
  short* pwt  = (short*)(ws + ((size_t)4 << 20) + (256 << 10));  // 16 MB bf16 pw_t
  float* p    = (float*)(ws + ((size_t)20 << 20) + (256 << 10)); // 4 MB leaf probs

  k_prep<<<4128, 256, 0, stream>>>(x, xbuf, gw, gwt, pw, pwt);
  k_gate<<<128, 256, 0, stream>>>(xbuf, gwt, gb, p);
  k_main<<<2048, 512, 0, stream>>>(xbuf, pwt, p, pb, out);
}